// Round 4
// baseline (275.031 us; speedup 1.0000x reference)
//
#include <hip/hip_runtime.h>

// LinearCRF: mean_b( logZ_b - gold_b ), B=8192, L=1024, S=3.
// Scaled linear-domain forward; lane owns an 8-step chunk per round (2 rounds
// of 512 steps), 6-stage ordered shfl_xor butterfly per round, PA*PB combine.
// R4: coalesced cooperative staging through bank-padded LDS. R1-R3 loaded
// per-lane chunks directly from global: 64 distinct cache lines per wave-load
// (lanes 192B apart) -> ~1280 scattered granule transactions/wave serialized
// in the memory pipe (runtime pinned at 64us, HBM 16%, VALU 28%). Now each
// wave issues unit-stride float4 loads (16 lines/instr) and redistributes
// via LDS. Padded strides 25/9 dwords (coprime 32) -> conflict-free readback.

#define LOG2E 1.4426950408889634f
#define LN2   0.6931471805599453f

constexpr int B = 8192;
constexpr int W = 4;             // waves per block
constexpr int EM_DW = 64 * 25;   // per-wave em: 24 floats + 1 pad per lane
constexpr int MK_DW = 64 * 9;    // per-wave mask: 8 floats + 1 pad per lane
constexpr int TG_DW = 128;       // per-wave tags: 512 tags packed 4/dword

__device__ __forceinline__ float fexp2(float x) { return __builtin_amdgcn_exp2f(x); }
__device__ __forceinline__ float flog2(float x) { return __builtin_amdgcn_logf(x); }

__device__ __forceinline__ float mux3(float a, float b, float c, int i) {
  return i == 0 ? a : (i == 1 ? b : c);
}
__device__ __forceinline__ float trmux(const float* __restrict__ T2, int p, int c) {
  const float r0 = mux3(T2[0], T2[1], T2[2], c);
  const float r1 = mux3(T2[3], T2[4], T2[5], c);
  const float r2 = mux3(T2[6], T2[7], T2[8], c);
  return mux3(r0, r1, r2, p);
}

__device__ __forceinline__ void matmul3(float* __restrict__ D,
                                        const float* __restrict__ A,
                                        const float* __restrict__ Bm) {
  #pragma unroll
  for (int i = 0; i < 3; ++i)
    #pragma unroll
    for (int j = 0; j < 3; ++j)
      D[i * 3 + j] = A[i * 3 + 0] * Bm[0 * 3 + j] +
                     A[i * 3 + 1] * Bm[1 * 3 + j] +
                     A[i * 3 + 2] * Bm[2 * 3 + j];
}

__device__ __forceinline__ void renorm3(float* __restrict__ P, float& scale) {
  float m = P[0];
  #pragma unroll
  for (int e = 1; e < 9; ++e) m = fmaxf(m, P[e]);
  int ex;
  (void)frexpf(m, &ex);
  #pragma unroll
  for (int e = 0; e < 9; ++e) P[e] = ldexpf(P[e], -ex);
  scale += (float)ex;
}

// Scatter one 512-step half (coalesced-loaded registers) into padded LDS.
__device__ __forceinline__ void stage(float* __restrict__ E, float* __restrict__ Mk,
                                      unsigned* __restrict__ Tg, int lane,
                                      const float4* __restrict__ vem,
                                      const float4* __restrict__ vmk,
                                      const int4* __restrict__ vtg) {
  #pragma unroll
  for (int u = 0; u < 6; ++u) {
    const int p = u * 64 + lane;                 // float4 index in half-row
    const int a = 4 * p + (int)((unsigned)p / 6u);  // = 25*(p/6) + 4*(p%6)
    const float4 v = vem[u];
    E[a + 0] = v.x; E[a + 1] = v.y; E[a + 2] = v.z; E[a + 3] = v.w;
  }
  #pragma unroll
  for (int u = 0; u < 2; ++u) {
    const int p = u * 64 + lane;
    const int a = 4 * p + (p >> 1);              // = 9*(p/2) + 4*(p%2)
    const float4 v = vmk[u];
    Mk[a + 0] = v.x; Mk[a + 1] = v.y; Mk[a + 2] = v.z; Mk[a + 3] = v.w;
  }
  #pragma unroll
  for (int u = 0; u < 2; ++u) {
    const int p = u * 64 + lane;
    const int4 t = vtg[u];
    Tg[p] = (unsigned)(t.x & 3) | ((unsigned)(t.y & 3) << 8) |
            ((unsigned)(t.z & 3) << 16) | ((unsigned)(t.w & 3) << 24);
  }
}

// One 512-step round: per-lane 8-step chunk product + gold partial + butterfly.
template <bool FIRST>
__device__ __forceinline__ void compute_round(
    const float* __restrict__ E, const float* __restrict__ Mk,
    const unsigned* __restrict__ Tg, int lane,
    const float* __restrict__ T2, const float* __restrict__ tk,
    float* __restrict__ Pout, float& scaleOut,
    float& gold, int& lastTag, int boundaryTag, float* __restrict__ a012) {
  const float* eml = E + 25 * lane;
  const float* mkl = Mk + 9 * lane;
  const unsigned t0 = Tg[2 * lane + 0];
  const unsigned t1 = Tg[2 * lane + 1];

  float P[9];
  float scale = 0.f;
  float e0sel = 0.f, mk0 = 0.f;
  int tag0 = 0, prev = 0;

  #pragma unroll
  for (int j = 0; j < 8; ++j) {
    const float ev0 = eml[3 * j + 0] * LOG2E;
    const float ev1 = eml[3 * j + 1] * LOG2E;
    const float ev2 = eml[3 * j + 2] * LOG2E;
    const float m = mkl[j];
    const unsigned tw = (j < 4) ? t0 : t1;
    const int cur = (int)((tw >> (8 * (j & 3))) & 3u);

    // gold (log2 domain); first step deferred (needs cross-lane prev tag)
    const float e = mux3(ev0, ev1, ev2, cur);
    if (j == 0) { e0sel = e; mk0 = m; tag0 = cur; }
    else        gold = fmaf(trmux(T2, prev, cur) + e, m, gold);
    prev = cur;

    // matrix step: M = act ? tk .* w_cols : I
    const float w0 = fexp2(ev0);
    const float w1 = fexp2(ev1);
    const float w2 = fexp2(ev2);
    if (FIRST && j == 0) { a012[0] = w0; a012[1] = w1; a012[2] = w2; }
    const bool act = (m > 0.f) && !(FIRST && j == 0 && lane == 0);  // t=0 is alpha0
    const float g = act ? 1.f : 0.f;
    const float c1 = 1.f - g;
    const float u0 = w0 * g, u1 = w1 * g, u2 = w2 * g;
    float M[9];
    M[0] = fmaf(tk[0], u0, c1); M[1] = tk[1] * u1;          M[2] = tk[2] * u2;
    M[3] = tk[3] * u0;          M[4] = fmaf(tk[4], u1, c1); M[5] = tk[5] * u2;
    M[6] = tk[6] * u0;          M[7] = tk[7] * u1;          M[8] = fmaf(tk[8], u2, c1);
    if (j == 0) {
      #pragma unroll
      for (int e2 = 0; e2 < 9; ++e2) P[e2] = M[e2];
    } else {
      float N[9];
      matmul3(N, P, M);
      #pragma unroll
      for (int e2 = 0; e2 < 9; ++e2) P[e2] = N[e2];
    }
  }
  renorm3(P, scale);

  // deferred first-step gold term
  const int prevLast = __shfl_up(prev, 1, 64);
  const int bt = (lane == 0) ? boundaryTag : prevLast;
  if (FIRST && lane == 0) gold = fmaf(e0sel, mk0, gold);
  else                    gold = fmaf(trmux(T2, bt, tag0) + e0sel, mk0, gold);
  lastTag = prev;

  // ordered butterfly combine (entries <= 3^6 = 729: no renorm needed)
  #pragma unroll
  for (int d = 1; d < 64; d <<= 1) {
    float o[9];
    #pragma unroll
    for (int e = 0; e < 9; ++e) o[e] = __shfl_xor(P[e], d, 64);
    const float osc = __shfl_xor(scale, d, 64);
    const bool later = (lane & d) != 0;
    float A[9], Bm[9];
    #pragma unroll
    for (int e = 0; e < 9; ++e) {
      A[e]  = later ? o[e] : P[e];
      Bm[e] = later ? P[e] : o[e];
    }
    float N[9];
    matmul3(N, A, Bm);
    #pragma unroll
    for (int e = 0; e < 9; ++e) P[e] = N[e];
    scale += osc;
  }
  #pragma unroll
  for (int e = 0; e < 9; ++e) Pout[e] = P[e];
  scaleOut = scale;
}

__global__ __launch_bounds__(256, 4) void crf_main(
    const float* __restrict__ em, const float* __restrict__ mask,
    const float* __restrict__ trans, const int* __restrict__ tags,
    float* __restrict__ out) {
  __shared__ float s_em[W][EM_DW];
  __shared__ float s_mk[W][MK_DW];
  __shared__ unsigned s_tg[W][TG_DW];
  __shared__ float red[W];

  const int lane = threadIdx.x & 63;
  const int wid = threadIdx.x >> 6;
  const int b = blockIdx.x * W + wid;

  const float4* em4 = (const float4*)(em + (size_t)b * 3072);
  const float4* mk4 = (const float4*)(mask + (size_t)b * 1024);
  const int4*   tg4 = (const int4*)(tags + (size_t)b * 1024);

  // ---- half 0: coalesced loads (unit stride across lanes) ----
  float4 aem[6], amk[2]; int4 atg[2];
  #pragma unroll
  for (int u = 0; u < 6; ++u) aem[u] = em4[u * 64 + lane];
  #pragma unroll
  for (int u = 0; u < 2; ++u) amk[u] = mk4[u * 64 + lane];
  #pragma unroll
  for (int u = 0; u < 2; ++u) atg[u] = tg4[u * 64 + lane];

  // transitions (uniform -> scalar path): log2 domain + linear form
  float T2[9], tk[9];
  #pragma unroll
  for (int e = 0; e < 9; ++e) {
    T2[e] = trans[e] * LOG2E;
    tk[e] = fexp2(T2[e]);
  }

  stage(s_em[wid], s_mk[wid], s_tg[wid], lane, aem, amk, atg);
  __syncthreads();

  // ---- prefetch half 1 while round 0 computes ----
  float4 pem[6], pmk[2]; int4 ptg[2];
  #pragma unroll
  for (int u = 0; u < 6; ++u) pem[u] = em4[384 + u * 64 + lane];
  #pragma unroll
  for (int u = 0; u < 2; ++u) pmk[u] = mk4[128 + u * 64 + lane];
  #pragma unroll
  for (int u = 0; u < 2; ++u) ptg[u] = tg4[128 + u * 64 + lane];

  float gold = 0.f;
  float a012[3];
  float PA[9], PB[9];
  float scA, scB;
  int lastA, lastB;

  compute_round<true>(s_em[wid], s_mk[wid], s_tg[wid], lane, T2, tk,
                      PA, scA, gold, lastA, 0, a012);

  stage(s_em[wid], s_mk[wid], s_tg[wid], lane, pem, pmk, ptg);
  __syncthreads();

  const int tag511 = __shfl(lastA, 63, 64);  // boundary tag for round-1 lane 0
  compute_round<false>(s_em[wid], s_mk[wid], s_tg[wid], lane, T2, tk,
                       PB, scB, gold, lastB, tag511, a012);

  // ---- combine halves + finalize ----
  #pragma unroll
  for (int d = 1; d < 64; d <<= 1) gold += __shfl_xor(gold, d, 64);

  if (lane == 0) {
    float P[9];
    matmul3(P, PA, PB);
    const float z = a012[0] * (P[0] + P[1] + P[2]) +
                    a012[1] * (P[3] + P[4] + P[5]) +
                    a012[2] * (P[6] + P[7] + P[8]);
    red[wid] = LN2 * (scA + scB + flog2(z) - gold);
  }
  __syncthreads();
  if (threadIdx.x == 0) {
    const float s = red[0] + red[1] + red[2] + red[3];
    atomicAdd(out, s * (1.0f / (float)B));
  }
}

extern "C" void kernel_launch(void* const* d_in, const int* in_sizes, int n_in,
                              void* d_out, int out_size, void* d_ws, size_t ws_size,
                              hipStream_t stream) {
  const float* em    = (const float*)d_in[0];
  const float* mask  = (const float*)d_in[1];
  const float* trans = (const float*)d_in[2];
  const int*   tags  = (const int*)d_in[3];
  float* out = (float*)d_out;

  hipMemsetAsync(out, 0, sizeof(float), stream);
  crf_main<<<B / W, 256, 0, stream>>>(em, mask, trans, tags, out);
}

// Round 5
// 227.122 us; speedup vs baseline: 1.2109x; 1.2109x over previous
//
#include <hip/hip_runtime.h>

// LinearCRF: mean_b( logZ_b - gold_b ), B=8192, L=1024, S=3.
// Scaled linear-domain forward. 1 wave = 1 sequence, processed in 4 quarters
// of 256 steps; each lane owns 4 consecutive steps per quarter.
// R5 structure: ALL global loads coalesced (unit-stride f4 across lanes).
// At 4 steps/lane, mask/tags coalesced loads are IDENTITY (lane l's f4 ==
// its own 4 steps) -- zero redistribution. Only em (12 dw/lane) goes through
// a tiny per-wave LDS scatter (stride-14 padded, b64 writes/reads, no
// barriers: same-wave DS ops are in-order). Prefetch depth = 1 quarter
// (20 dwords) double-buffered = 40 regs, fits the (256,4) 128-VGPR cap
// (R4 spilled 238 MB scratch with 80-reg half-granularity prefetch).
// Per quarter: 4-step chunk product -> renorm -> 6-stage ordered shfl_xor
// butterfly -> Pacc *= Pq. Gold score fused. Block reduce + atomicAdd.

#define LOG2E 1.4426950408889634f
#define LN2   0.6931471805599453f

constexpr int B = 8192;
constexpr int W = 4;          // waves per block
constexpr int LSTRIDE = 14;   // LDS dwords/lane: 12 data + 2 pad (even -> b64)

__device__ __forceinline__ float fexp2(float x) { return __builtin_amdgcn_exp2f(x); }
__device__ __forceinline__ float flog2(float x) { return __builtin_amdgcn_logf(x); }

__device__ __forceinline__ float mux3(float a, float b, float c, int i) {
  return i == 0 ? a : (i == 1 ? b : c);
}
__device__ __forceinline__ float trmux(const float* __restrict__ T2, int p, int c) {
  const float r0 = mux3(T2[0], T2[1], T2[2], c);
  const float r1 = mux3(T2[3], T2[4], T2[5], c);
  const float r2 = mux3(T2[6], T2[7], T2[8], c);
  return mux3(r0, r1, r2, p);
}

__device__ __forceinline__ void matmul3(float* __restrict__ D,
                                        const float* __restrict__ A,
                                        const float* __restrict__ Bm) {
  #pragma unroll
  for (int i = 0; i < 3; ++i)
    #pragma unroll
    for (int j = 0; j < 3; ++j)
      D[i * 3 + j] = A[i * 3 + 0] * Bm[0 * 3 + j] +
                     A[i * 3 + 1] * Bm[1 * 3 + j] +
                     A[i * 3 + 2] * Bm[2 * 3 + j];
}

// Exact power-of-2 renormalization: P *= 2^-ex, scale += ex.
__device__ __forceinline__ void renorm3(float* __restrict__ P, float& scale) {
  float m = P[0];
  #pragma unroll
  for (int e = 1; e < 9; ++e) m = fmaxf(m, P[e]);
  int ex;
  (void)frexpf(m, &ex);
  #pragma unroll
  for (int e = 0; e < 9; ++e) P[e] = ldexpf(P[e], -ex);
  scale += (float)ex;
}

__global__ __launch_bounds__(256, 4) void crf_main(
    const float* __restrict__ em, const float* __restrict__ mask,
    const float* __restrict__ trans, const int* __restrict__ tags,
    float* __restrict__ out) {
  __shared__ __align__(16) float s_em[W][64 * LSTRIDE];  // 3584 B per wave
  __shared__ float red[W];

  const int lane = threadIdx.x & 63;
  const int wid  = threadIdx.x >> 6;
  const int b    = blockIdx.x * W + wid;
  float* lds = s_em[wid];

  const float4* em4 = (const float4*)(em + (size_t)b * 3072);
  const float4* mk4 = (const float4*)(mask + (size_t)b * 1024);
  const int4*   tg4 = (const int4*)(tags + (size_t)b * 1024);

  // ---- preload quarters 0 and 1 (coalesced; 20 dwords per quarter) ----
  float4 em_r[2][3]; float4 mk_r[2]; int4 tg_r[2];
  #pragma unroll
  for (int u = 0; u < 3; ++u) em_r[0][u] = em4[u * 64 + lane];
  mk_r[0] = mk4[lane];
  tg_r[0] = tg4[lane];
  #pragma unroll
  for (int u = 0; u < 3; ++u) em_r[1][u] = em4[192 + u * 64 + lane];
  mk_r[1] = mk4[64 + lane];
  tg_r[1] = tg4[64 + lane];

  // transitions (wave-uniform -> scalar): log2 domain + linear form
  float T2[9], tk[9];
  #pragma unroll
  for (int e = 0; e < 9; ++e) { T2[e] = trans[e] * LOG2E; tk[e] = fexp2(T2[e]); }

  float Pacc[9];
  float scale = 0.f, gold = 0.f;
  float a0 = 0.f, a1 = 0.f, a2 = 0.f;  // step-0 linear emissions (lane 0 valid)
  int boundaryTag = 0;                 // tag of last step of previous quarter

  #pragma unroll
  for (int q = 0; q < 4; ++q) {
    const int buf = q & 1;

    // ---- scatter em quarter into padded LDS (b64 pairs) ----
    // f4 index K=u*64+lane holds quarter dwords [4K,4K+4); target lane K/3,
    // offset 4*(K%3) in {0,4,8} -> both b64 pairs land in one lane's block.
    #pragma unroll
    for (int u = 0; u < 3; ++u) {
      const float4 v = em_r[buf][u];
      const int t  = u + lane;            // K = 64u+lane: K%3=(u+lane)%3,
      const int l0 = 21 * u + t / 3;      //               K/3=21u+(u+lane)/3
      const int r0 = 4 * (t % 3);
      float2* wp = (float2*)&lds[l0 * LSTRIDE + r0];
      wp[0] = make_float2(v.x, v.y);
      wp[1] = make_float2(v.z, v.w);
    }

    const float mf[4] = {mk_r[buf].x, mk_r[buf].y, mk_r[buf].z, mk_r[buf].w};
    const int   tf[4] = {tg_r[buf].x, tg_r[buf].y, tg_r[buf].z, tg_r[buf].w};

    float P[9];
    float e0sel = 0.f, mk0 = 0.f;
    int tag0 = 0, prev = 0;
    const float2* rp = (const float2*)&lds[lane * LSTRIDE];

    #pragma unroll
    for (int h = 0; h < 2; ++h) {       // two steps per half -> 6 LDS dwords
      float eb[6];
      #pragma unroll
      for (int r = 0; r < 3; ++r) {
        const float2 t = rp[3 * h + r];
        eb[2 * r] = t.x; eb[2 * r + 1] = t.y;
      }
      #pragma unroll
      for (int jj = 0; jj < 2; ++jj) {
        const int j = 2 * h + jj;
        const float ev0 = eb[3 * jj + 0] * LOG2E;
        const float ev1 = eb[3 * jj + 1] * LOG2E;
        const float ev2 = eb[3 * jj + 2] * LOG2E;
        const float m = mf[j];
        const int cur = tf[j];

        // gold (log2 domain); j=0 deferred (needs cross-lane prev tag)
        const float e = mux3(ev0, ev1, ev2, cur);
        if (j == 0) { e0sel = e; mk0 = m; tag0 = cur; }
        else        gold = fmaf(trmux(T2, prev, cur) + e, m, gold);
        prev = cur;

        // matrix step: M = act ? tk .* w_cols : I
        const float w0 = fexp2(ev0), w1 = fexp2(ev1), w2 = fexp2(ev2);
        if (q == 0 && j == 0) { a0 = w0; a1 = w1; a2 = w2; }
        const bool act = (m > 0.f) && !(q == 0 && j == 0 && lane == 0);
        const float g = act ? 1.f : 0.f;
        const float c1 = 1.f - g;
        const float u0 = w0 * g, u1 = w1 * g, u2 = w2 * g;
        float M[9];
        M[0] = fmaf(tk[0], u0, c1); M[1] = tk[1] * u1;          M[2] = tk[2] * u2;
        M[3] = tk[3] * u0;          M[4] = fmaf(tk[4], u1, c1); M[5] = tk[5] * u2;
        M[6] = tk[6] * u0;          M[7] = tk[7] * u1;          M[8] = fmaf(tk[8], u2, c1);
        if (j == 0) {
          #pragma unroll
          for (int e2 = 0; e2 < 9; ++e2) P[e2] = M[e2];
        } else {
          float N[9];
          matmul3(N, P, M);
          #pragma unroll
          for (int e2 = 0; e2 < 9; ++e2) P[e2] = N[e2];
        }
      }
    }

    // deferred j=0 gold term (prev tag from lane-1 / quarter boundary)
    const int prevLast = __shfl_up(prev, 1, 64);
    const int bt = (lane == 0) ? boundaryTag : prevLast;
    const float tr0 = trmux(T2, bt, tag0);
    const float tplus = (q == 0 && lane == 0) ? 0.f : tr0;  // t=0: emission only
    gold = fmaf(tplus + e0sel, mk0, gold);
    boundaryTag = __shfl(prev, 63, 64);

    // ---- renorm + ordered butterfly (quarter product in every lane) ----
    float sc = 0.f;
    renorm3(P, sc);
    #pragma unroll
    for (int d = 1; d < 64; d <<= 1) {
      float o[9];
      #pragma unroll
      for (int e2 = 0; e2 < 9; ++e2) o[e2] = __shfl_xor(P[e2], d, 64);
      const float osc = __shfl_xor(sc, d, 64);
      const bool later = (lane & d) != 0;
      float A[9], Bm[9];
      #pragma unroll
      for (int e2 = 0; e2 < 9; ++e2) {
        A[e2]  = later ? o[e2] : P[e2];
        Bm[e2] = later ? P[e2] : o[e2];
      }
      float N[9];
      matmul3(N, A, Bm);
      #pragma unroll
      for (int e2 = 0; e2 < 9; ++e2) P[e2] = N[e2];
      sc += osc;
    }
    scale += sc;

    if (q == 0) {
      #pragma unroll
      for (int e2 = 0; e2 < 9; ++e2) Pacc[e2] = P[e2];
    } else {
      float N[9];
      matmul3(N, Pacc, P);
      #pragma unroll
      for (int e2 = 0; e2 < 9; ++e2) Pacc[e2] = N[e2];
    }

    // ---- prefetch quarter q+2 into the freed buffer ----
    if (q < 2) {
      #pragma unroll
      for (int u = 0; u < 3; ++u) em_r[buf][u] = em4[(q + 2) * 192 + u * 64 + lane];
      mk_r[buf] = mk4[(q + 2) * 64 + lane];
      tg_r[buf] = tg4[(q + 2) * 64 + lane];
    }
  }

  // ---- finalize ----
  #pragma unroll
  for (int d = 1; d < 64; d <<= 1) gold += __shfl_xor(gold, d, 64);

  if (lane == 0) {
    const float z = a0 * (Pacc[0] + Pacc[1] + Pacc[2]) +
                    a1 * (Pacc[3] + Pacc[4] + Pacc[5]) +
                    a2 * (Pacc[6] + Pacc[7] + Pacc[8]);
    red[wid] = LN2 * (scale + flog2(z) - gold);
  }
  __syncthreads();
  if (threadIdx.x == 0) {
    const float s = red[0] + red[1] + red[2] + red[3];
    atomicAdd(out, s * (1.0f / (float)B));
  }
}

extern "C" void kernel_launch(void* const* d_in, const int* in_sizes, int n_in,
                              void* d_out, int out_size, void* d_ws, size_t ws_size,
                              hipStream_t stream) {
  const float* em    = (const float*)d_in[0];
  const float* mask  = (const float*)d_in[1];
  const float* trans = (const float*)d_in[2];
  const int*   tags  = (const int*)d_in[3];
  float* out = (float*)d_out;

  hipMemsetAsync(out, 0, sizeof(float), stream);
  crf_main<<<B / W, 256, 0, stream>>>(em, mask, trans, tags, out);
}

// Round 6
// 216.741 us; speedup vs baseline: 1.2689x; 1.0479x over previous
//
#include <hip/hip_runtime.h>

// LinearCRF: mean_b( logZ_b - gold_b ), B=8192, L=1024, S=3.
// Scaled linear-domain forward. 1 wave = 1 sequence, 2 halves of 512 steps,
// 8 steps per lane per half. Coalesced unit-stride f4 loads; redistribution
// through odd-stride padded LDS (em 25, mask 9, tags packed 3 — coprime 32,
// conflict-free). Hillis-Steele matrix scan (lane 63 ends with half product).
// R6 hard rule: NO private arrays with runtime/buffered indexing — R1/R4/R5
// scratch traffic (65/238/71 MB writes at VGPR=64) was private arrays
// lowered to scratch, not allocator spills. All buffers are named float4s.

#define LOG2E 1.4426950408889634f
#define LN2   0.6931471805599453f

constexpr int B = 8192;
constexpr int W = 4;        // waves per block
constexpr int EM_ST = 25;   // LDS dwords/lane: 24 em + 1 pad (odd)
constexpr int MK_ST = 9;    // 8 mask + 1 pad (odd)
constexpr int TG_ST = 3;    // 2 packed-tag dwords + 1 pad (odd)

__device__ __forceinline__ float fexp2(float x) { return __builtin_amdgcn_exp2f(x); }
__device__ __forceinline__ float flog2(float x) { return __builtin_amdgcn_logf(x); }

__device__ __forceinline__ float mux3(float a, float b, float c, int i) {
  return i == 0 ? a : (i == 1 ? b : c);
}
__device__ __forceinline__ float trmux(const float* __restrict__ T2, int p, int c) {
  const float r0 = mux3(T2[0], T2[1], T2[2], c);
  const float r1 = mux3(T2[3], T2[4], T2[5], c);
  const float r2 = mux3(T2[6], T2[7], T2[8], c);
  return mux3(r0, r1, r2, p);
}

__device__ __forceinline__ void matmul3(float* __restrict__ D,
                                        const float* __restrict__ A,
                                        const float* __restrict__ Bm) {
  #pragma unroll
  for (int i = 0; i < 3; ++i)
    #pragma unroll
    for (int j = 0; j < 3; ++j)
      D[i * 3 + j] = A[i * 3 + 0] * Bm[0 * 3 + j] +
                     A[i * 3 + 1] * Bm[1 * 3 + j] +
                     A[i * 3 + 2] * Bm[2 * 3 + j];
}

// Exact power-of-2 renormalization: P *= 2^-ex, scale += ex.
__device__ __forceinline__ void renorm3(float* __restrict__ P, float& scale) {
  float m = P[0];
  #pragma unroll
  for (int e = 1; e < 9; ++e) m = fmaxf(m, P[e]);
  int ex;
  (void)frexpf(m, &ex);
  #pragma unroll
  for (int e = 0; e < 9; ++e) P[e] = ldexpf(P[e], -ex);
  scale += (float)ex;
}

// ---- LDS scatter: coalesced f4 (index K=64u+lane) -> owner-lane layout ----
// em: owner lane D/24 of half-dword D=4K..4K+3; all 4 in one lane (4K%24 in
// {0,4,8,12,16,20}). Fold LOG2E here.
__device__ __forceinline__ void scat_em(float* __restrict__ L, int lane, int u, float4 v) {
  const int K = 64 * u + lane;
  const int a = EM_ST * (K / 6) + 4 * (K % 6);
  L[a + 0] = v.x * LOG2E; L[a + 1] = v.y * LOG2E;
  L[a + 2] = v.z * LOG2E; L[a + 3] = v.w * LOG2E;
}
__device__ __forceinline__ void scat_mk(float* __restrict__ L, int lane, int u, float4 v) {
  const int K = 64 * u + lane;
  const int a = MK_ST * (K >> 1) + 4 * (K & 1);
  L[a + 0] = v.x; L[a + 1] = v.y; L[a + 2] = v.z; L[a + 3] = v.w;
}
__device__ __forceinline__ void scat_tg(unsigned* __restrict__ L, int lane, int u, int4 t) {
  const int K = 64 * u + lane;
  const unsigned pk = (unsigned)(t.x & 3) | ((unsigned)(t.y & 3) << 8) |
                      ((unsigned)(t.z & 3) << 16) | ((unsigned)(t.w & 3) << 24);
  L[TG_ST * (K >> 1) + (K & 1)] = pk;
}

// One 512-step half: 8-step chunk product + gold partial + matrix scan.
// Pout/scOut valid in lane 63 (full half product).
template <int H>
__device__ __forceinline__ void compute_half(
    const float* __restrict__ Lem, const float* __restrict__ Lmk,
    const unsigned* __restrict__ Ltg, int lane,
    const float* __restrict__ T2, const float* __restrict__ tk,
    float* __restrict__ Pout, float& scOut,
    float& gold, int& boundaryTag, float& a0, float& a1, float& a2) {
  const float* eml = Lem + EM_ST * lane;
  const float* mkl = Lmk + MK_ST * lane;
  const unsigned pk0 = Ltg[TG_ST * lane + 0];
  const unsigned pk1 = Ltg[TG_ST * lane + 1];

  float P[9];
  float e0sel = 0.f, mk0 = 0.f;
  int tag0 = 0, prev = 0;

  #pragma unroll
  for (int j = 0; j < 8; ++j) {
    const float ev0 = eml[3 * j + 0];   // already *LOG2E from scatter
    const float ev1 = eml[3 * j + 1];
    const float ev2 = eml[3 * j + 2];
    const float m = mkl[j];
    const int cur = (int)(((j < 4 ? pk0 : pk1) >> (8 * (j & 3))) & 3u);

    // gold (log2 domain); j=0 deferred (needs cross-lane prev tag)
    const float e = mux3(ev0, ev1, ev2, cur);
    if (j == 0) { e0sel = e; mk0 = m; tag0 = cur; }
    else        gold = fmaf(trmux(T2, prev, cur) + e, m, gold);
    prev = cur;

    // matrix step: M = act ? tk .* w_cols : I
    const float w0 = fexp2(ev0), w1 = fexp2(ev1), w2 = fexp2(ev2);
    if (H == 0 && j == 0) { a0 = w0; a1 = w1; a2 = w2; }
    const bool act = (m > 0.f) && !(H == 0 && j == 0 && lane == 0);  // t=0 is alpha0
    const float g = act ? 1.f : 0.f;
    const float c1 = 1.f - g;
    const float u0 = w0 * g, u1 = w1 * g, u2 = w2 * g;
    float M[9];
    M[0] = fmaf(tk[0], u0, c1); M[1] = tk[1] * u1;          M[2] = tk[2] * u2;
    M[3] = tk[3] * u0;          M[4] = fmaf(tk[4], u1, c1); M[5] = tk[5] * u2;
    M[6] = tk[6] * u0;          M[7] = tk[7] * u1;          M[8] = fmaf(tk[8], u2, c1);
    if (j == 0) {
      #pragma unroll
      for (int e2 = 0; e2 < 9; ++e2) P[e2] = M[e2];
    } else {
      float N[9];
      matmul3(N, P, M);
      #pragma unroll
      for (int e2 = 0; e2 < 9; ++e2) P[e2] = N[e2];
    }
  }

  // deferred j=0 gold term
  const int prevLast = __shfl_up(prev, 1, 64);
  const int bt = (lane == 0) ? boundaryTag : prevLast;
  const float tr0 = trmux(T2, bt, tag0);
  const float tplus = (H == 0 && lane == 0) ? 0.f : tr0;  // t=0: emission only
  gold = fmaf(tplus + e0sel, mk0, gold);
  boundaryTag = __shfl(prev, 63, 64);

  float sc = 0.f;
  renorm3(P, sc);

  // Hillis-Steele inclusive scan: P_l <- (prefix of earlier lanes) * P_l.
  #pragma unroll
  for (int d = 1; d < 64; d <<= 1) {
    float o0 = __shfl_up(P[0], d, 64), o1 = __shfl_up(P[1], d, 64);
    float o2 = __shfl_up(P[2], d, 64), o3 = __shfl_up(P[3], d, 64);
    float o4 = __shfl_up(P[4], d, 64), o5 = __shfl_up(P[5], d, 64);
    float o6 = __shfl_up(P[6], d, 64), o7 = __shfl_up(P[7], d, 64);
    float o8 = __shfl_up(P[8], d, 64);
    float osc = __shfl_up(sc, d, 64);
    const bool in = (lane >= d);
    float O[9];
    O[0] = in ? o0 : 1.f; O[1] = in ? o1 : 0.f; O[2] = in ? o2 : 0.f;
    O[3] = in ? o3 : 0.f; O[4] = in ? o4 : 1.f; O[5] = in ? o5 : 0.f;
    O[6] = in ? o6 : 0.f; O[7] = in ? o7 : 0.f; O[8] = in ? o8 : 1.f;
    float N[9];
    matmul3(N, O, P);   // earlier segment on the LEFT
    #pragma unroll
    for (int e2 = 0; e2 < 9; ++e2) P[e2] = N[e2];
    sc += in ? osc : 0.f;
  }
  #pragma unroll
  for (int e2 = 0; e2 < 9; ++e2) Pout[e2] = P[e2];
  scOut = sc;
}

__global__ __launch_bounds__(256, 4) void crf_main(
    const float* __restrict__ em, const float* __restrict__ mask,
    const float* __restrict__ trans, const int* __restrict__ tags,
    float* __restrict__ out) {
  __shared__ float    s_em[W][64 * EM_ST];   // 6400 B/wave
  __shared__ float    s_mk[W][64 * MK_ST];   // 2304 B/wave
  __shared__ unsigned s_tg[W][64 * TG_ST];   //  768 B/wave
  __shared__ float red[W];

  const int lane = threadIdx.x & 63;
  const int wid  = threadIdx.x >> 6;
  const int b    = blockIdx.x * W + wid;
  float*    Lem = s_em[wid];
  float*    Lmk = s_mk[wid];
  unsigned* Ltg = s_tg[wid];

  const float4* em4 = (const float4*)(em + (size_t)b * 3072);
  const float4* mk4 = (const float4*)(mask + (size_t)b * 1024);
  const int4*   tg4 = (const int4*)(tags + (size_t)b * 1024);

  // ---- half-0 loads (coalesced, unit stride across lanes) ----
  const float4 e0 = em4[lane],        e1 = em4[64 + lane],  e2 = em4[128 + lane];
  const float4 e3 = em4[192 + lane],  e4 = em4[256 + lane], e5 = em4[320 + lane];
  const float4 m0 = mk4[lane],        m1 = mk4[64 + lane];
  const int4   t0 = tg4[lane],        t1 = tg4[64 + lane];

  // transitions (wave-uniform): log2 domain + linear form
  float T2[9], tk[9];
  #pragma unroll
  for (int e = 0; e < 9; ++e) { T2[e] = trans[e] * LOG2E; tk[e] = fexp2(T2[e]); }

  // scatter half 0
  scat_em(Lem, lane, 0, e0); scat_em(Lem, lane, 1, e1); scat_em(Lem, lane, 2, e2);
  scat_em(Lem, lane, 3, e3); scat_em(Lem, lane, 4, e4); scat_em(Lem, lane, 5, e5);
  scat_mk(Lmk, lane, 0, m0); scat_mk(Lmk, lane, 1, m1);
  scat_tg(Ltg, lane, 0, t0); scat_tg(Ltg, lane, 1, t1);

  // ---- half-1 loads in flight during half-0 compute ----
  const float4 f0 = em4[384 + lane], f1 = em4[448 + lane], f2 = em4[512 + lane];
  const float4 f3 = em4[576 + lane], f4v = em4[640 + lane], f5 = em4[704 + lane];
  const float4 n0 = mk4[128 + lane], n1 = mk4[192 + lane];
  const int4   s0 = tg4[128 + lane], s1 = tg4[192 + lane];

  float gold = 0.f;
  int boundaryTag = 0;
  float a0 = 0.f, a1 = 0.f, a2 = 0.f;
  float PA[9], PB[9];
  float scA, scB;

  compute_half<0>(Lem, Lmk, Ltg, lane, T2, tk, PA, scA, gold, boundaryTag, a0, a1, a2);

  // scatter half 1 (same-wave DS program order: safe to reuse the buffer)
  scat_em(Lem, lane, 0, f0); scat_em(Lem, lane, 1, f1); scat_em(Lem, lane, 2, f2);
  scat_em(Lem, lane, 3, f3); scat_em(Lem, lane, 4, f4v); scat_em(Lem, lane, 5, f5);
  scat_mk(Lmk, lane, 0, n0); scat_mk(Lmk, lane, 1, n1);
  scat_tg(Ltg, lane, 0, s0); scat_tg(Ltg, lane, 1, s1);

  compute_half<1>(Lem, Lmk, Ltg, lane, T2, tk, PB, scB, gold, boundaryTag, a0, a1, a2);

  // ---- finalize on lane 63 (holds both half products) ----
  #pragma unroll
  for (int d = 1; d < 64; d <<= 1) gold += __shfl_xor(gold, d, 64);
  const float af0 = __shfl(a0, 0, 64);
  const float af1 = __shfl(a1, 0, 64);
  const float af2 = __shfl(a2, 0, 64);

  if (lane == 63) {
    float Pt[9];
    matmul3(Pt, PA, PB);
    const float z = af0 * (Pt[0] + Pt[1] + Pt[2]) +
                    af1 * (Pt[3] + Pt[4] + Pt[5]) +
                    af2 * (Pt[6] + Pt[7] + Pt[8]);
    red[wid] = LN2 * (scA + scB + flog2(z) - gold);
  }
  __syncthreads();
  if (threadIdx.x == 0) {
    const float s = red[0] + red[1] + red[2] + red[3];
    atomicAdd(out, s * (1.0f / (float)B));
  }
}

extern "C" void kernel_launch(void* const* d_in, const int* in_sizes, int n_in,
                              void* d_out, int out_size, void* d_ws, size_t ws_size,
                              hipStream_t stream) {
  const float* em    = (const float*)d_in[0];
  const float* mask  = (const float*)d_in[1];
  const float* trans = (const float*)d_in[2];
  const int*   tags  = (const int*)d_in[3];
  float* out = (float*)d_out;

  hipMemsetAsync(out, 0, sizeof(float), stream);
  crf_main<<<B / W, 256, 0, stream>>>(em, mask, trans, tags, out);
}